// Round 4
// baseline (518.080 us; speedup 1.0000x reference)
//
#include <hip/hip_runtime.h>
#include <math.h>

// Problem constants (BaseSpectrogram1D)
#define L_LEN    131072
#define M_FRAMES 511
#define N_FFT    512
#define KH       257
#define FSTRIDE  256
#define B_BATCH  128

#define TM   24      // frames per block
#define NPAD 260     // padded LDS row stride (floats); row bytes = 1040 (16B-aligned)
#define SQRT_N 22.62741699796952f  // sqrt(512)

// HW sincos: v_sin_f32/v_cos_f32 take input in REVOLUTIONS (sin(x*2pi)).
// Phase p = (n*k) mod 512 reduced exactly in integer => rev = p/512 exact fp32.
__device__ __forceinline__ float hw_sin_rev(float rev) {
    float r; asm("v_sin_f32 %0, %1" : "=v"(r) : "v"(rev)); return r;
}
__device__ __forceinline__ float hw_cos_rev(float rev) {
    float r; asm("v_cos_f32 %0, %1" : "=v"(r) : "v"(rev)); return r;
}

// ---------------------------------------------------------------------------
// Kernel 1: per-batch-row mean (deterministic tree reduction)
// ---------------------------------------------------------------------------
__global__ __launch_bounds__(1024) void mean_kernel(const float* __restrict__ x,
                                                    float* __restrict__ means) {
    const int b = blockIdx.x;
    const float4* row = (const float4*)(x + (size_t)b * L_LEN);
    float s = 0.f;
    const int nvec = L_LEN / 4;  // 32768
    for (int i = threadIdx.x; i < nvec; i += 1024) {
        float4 v = row[i];
        s += (v.x + v.y) + (v.z + v.w);
    }
    for (int off = 32; off > 0; off >>= 1) s += __shfl_down(s, off, 64);
    __shared__ float wsum[16];
    const int wid = threadIdx.x >> 6, lane = threadIdx.x & 63;
    if (lane == 0) wsum[wid] = s;
    __syncthreads();
    if (threadIdx.x == 0) {
        float t = 0.f;
        #pragma unroll
        for (int i = 0; i < 16; ++i) t += wsum[i];
        means[b] = t / (float)L_LEN;
    }
}

// ---------------------------------------------------------------------------
// Kernel 2: windowed DFT magnitude, Hermitian-paired, coefficients on device.
//   f[n] = (x[m*256+n]-mean)*w[n]
//   E[n] = S*(f[n]+f[512-n]), O[n] = S*(f[n]-f[512-n]), n=1..255  (S=sqrt 512)
//   E[0] = S*f[0], O[0] = S*f[256]
//   re[k] = E[0] + (-1)^k*O[0] + sum_n E[n]*cos(2pi n k/512)
//   im[k] =                      sum_n O[n]*sin(2pi n k/512)   (sign-flip ok under abs)
//   k=256: coefficients (-1)^n, pure real (alternating sum).
// Block: (b, frame-tile TM). 256 threads; thread t owns bin k=t.
// ---------------------------------------------------------------------------
__global__ __launch_bounds__(256) void spec_kernel(const float* __restrict__ x,
                                                   const float* __restrict__ w,
                                                   const float* __restrict__ means,
                                                   float* __restrict__ out) {
    __shared__ __align__(16) float E[TM][NPAD];
    __shared__ __align__(16) float O[TM][NPAD];
    __shared__ float wl[N_FFT];

    const int b  = blockIdx.x;
    const int m0 = blockIdx.y * TM;
    const int t  = threadIdx.x;  // 0..255
    const float mean = means[b];

    wl[t]       = w[t];
    wl[t + 256] = w[t + 256];
    __syncthreads();

    const float* xb = x + (size_t)b * L_LEN;
    const int nf = min(TM, M_FRAMES - m0);

    // Build scaled E/O per frame; thread t handles pair index t.
    for (int f = 0; f < nf; ++f) {
        const float* xf = xb + (size_t)(m0 + f) * FSTRIDE;
        if (t == 0) {
            E[f][0] = SQRT_N * ((xf[0]   - mean) * wl[0]);
            O[f][0] = SQRT_N * ((xf[256] - mean) * wl[256]);
        } else {
            float a = (xf[t]       - mean) * wl[t];
            float c = (xf[512 - t] - mean) * wl[512 - t];
            E[f][t] = SQRT_N * (a + c);
            O[f][t] = SQRT_N * (a - c);
        }
    }
    __syncthreads();

    const int k = t;
    const float sgn = (k & 1) ? -1.0f : 1.0f;
    float re[TM], im[TM];

    // prologue: group j=0 covers n=0 (DC term), n=1..3 (regular terms)
    {
        float c1, s1, c2, s2, c3, s3;
        int p1 = k;
        int p2 = (p1 + k) & 511;
        int p3 = (p2 + k) & 511;
        c1 = hw_cos_rev((float)p1 * (1.0f/512.0f));
        s1 = hw_sin_rev((float)p1 * (1.0f/512.0f));
        c2 = hw_cos_rev((float)p2 * (1.0f/512.0f));
        s2 = hw_sin_rev((float)p2 * (1.0f/512.0f));
        c3 = hw_cos_rev((float)p3 * (1.0f/512.0f));
        s3 = hw_sin_rev((float)p3 * (1.0f/512.0f));
        #pragma unroll
        for (int f = 0; f < TM; ++f) {
            float4 e4 = *(const float4*)&E[f][0];  // broadcast b128
            float4 o4 = *(const float4*)&O[f][0];
            float r = fmaf(sgn, o4.x, e4.x);       // E0 + (-1)^k * O0
            float i2 = 0.0f;
            r  = fmaf(e4.y, c1, r);  i2 = fmaf(o4.y, s1, i2);
            r  = fmaf(e4.z, c2, r);  i2 = fmaf(o4.z, s2, i2);
            r  = fmaf(e4.w, c3, r);  i2 = fmaf(o4.w, s3, i2);
            re[f] = r; im[f] = i2;
        }
    }

    // main: groups j=1..63 cover n=4j..4j+3
    int p = (4 * k) & 511;  // phase of n=4
    for (int j = 1; j < 64; ++j) {
        float cc[4], ss[4];
        int pp = p;
        #pragma unroll
        for (int u = 0; u < 4; ++u) {
            float rev = (float)pp * (1.0f/512.0f);
            cc[u] = hw_cos_rev(rev);
            ss[u] = hw_sin_rev(rev);
            pp = (pp + k) & 511;
        }
        p = pp;
        #pragma unroll
        for (int f = 0; f < TM; ++f) {
            float4 e4 = *(const float4*)&E[f][4 * j];  // broadcast b128
            float4 o4 = *(const float4*)&O[f][4 * j];
            re[f] = fmaf(e4.x, cc[0], re[f]);  im[f] = fmaf(o4.x, ss[0], im[f]);
            re[f] = fmaf(e4.y, cc[1], re[f]);  im[f] = fmaf(o4.y, ss[1], im[f]);
            re[f] = fmaf(e4.z, cc[2], re[f]);  im[f] = fmaf(o4.z, ss[2], im[f]);
            re[f] = fmaf(e4.w, cc[3], re[f]);  im[f] = fmaf(o4.w, ss[3], im[f]);
        }
    }

    // store k = 0..255 (static indexing, predicated)
    #pragma unroll
    for (int f = 0; f < TM; ++f) {
        if (f < nf) {
            float r = re[f], i2 = im[f];
            out[((size_t)b * M_FRAMES + (m0 + f)) * KH + k] = sqrtf(fmaf(r, r, i2 * i2));
        }
    }

    // k = 256 (Nyquist bin): coefficients (-1)^n, pure real
    if (t < nf) {
        const int f = t;
        float acc = E[f][0] + O[f][0];
        for (int n = 1; n < 255; n += 2) {
            acc += E[f][n + 1] - E[f][n];
        }
        acc -= E[f][255];
        out[((size_t)b * M_FRAMES + (m0 + f)) * KH + 256] = fabsf(acc);
    }
}

// ---------------------------------------------------------------------------
extern "C" void kernel_launch(void* const* d_in, const int* in_sizes, int n_in,
                              void* d_out, int out_size, void* d_ws, size_t ws_size,
                              hipStream_t stream) {
    const float* x = (const float*)d_in[0];
    const float* w = (const float*)d_in[1];
    float* out   = (float*)d_out;
    float* means = (float*)d_ws;  // 128 floats

    mean_kernel<<<dim3(B_BATCH), dim3(1024), 0, stream>>>(x, means);

    const int mtiles = (M_FRAMES + TM - 1) / TM;  // 22
    spec_kernel<<<dim3(B_BATCH, mtiles), dim3(256), 0, stream>>>(x, w, means, out);
}

// Round 7
// 371.580 us; speedup vs baseline: 1.3943x; 1.3943x over previous
//
#include <hip/hip_runtime.h>
#include <math.h>

// Problem constants (BaseSpectrogram1D)
#define L_LEN    131072
#define M_FRAMES 511
#define N_FFT    512
#define KH       257
#define FSTRIDE  256
#define B_BATCH  128

#define TM       32    // frames per block
#define RSTRIDE  36    // floats per LDS row: 144 B -> 16B-aligned rows, bank-spread writes
#define SQRT_N   22.62741699796952f  // sqrt(512)

// v_sin/cos_f32 take input in REVOLUTIONS. p = (n*k)&511 exact int -> rev exact fp32.
__device__ __forceinline__ float hw_sin_rev(float rev) {
    float r; asm("v_sin_f32 %0, %1" : "=v"(r) : "v"(rev)); return r;
}
__device__ __forceinline__ float hw_cos_rev(float rev) {
    float r; asm("v_cos_f32 %0, %1" : "=v"(r) : "v"(rev)); return r;
}

// ---------------------------------------------------------------------------
// Kernel 1: per-batch-row mean (deterministic tree reduction)
// ---------------------------------------------------------------------------
__global__ __launch_bounds__(1024) void mean_kernel(const float* __restrict__ x,
                                                    float* __restrict__ means) {
    const int b = blockIdx.x;
    const float4* row = (const float4*)(x + (size_t)b * L_LEN);
    float s = 0.f;
    const int nvec = L_LEN / 4;
    for (int i = threadIdx.x; i < nvec; i += 1024) {
        float4 v = row[i];
        s += (v.x + v.y) + (v.z + v.w);
    }
    for (int off = 32; off > 0; off >>= 1) s += __shfl_down(s, off, 64);
    __shared__ float wsum[16];
    const int wid = threadIdx.x >> 6, lane = threadIdx.x & 63;
    if (lane == 0) wsum[wid] = s;
    __syncthreads();
    if (threadIdx.x == 0) {
        float t = 0.f;
        #pragma unroll
        for (int i = 0; i < 16; ++i) t += wsum[i];
        means[b] = t / (float)L_LEN;
    }
}

// ---------------------------------------------------------------------------
// Kernel 2: Hermitian-paired windowed DFT magnitude, register-tiled.
//   E[n] = S*(f[n]+f[512-n]), O[n] = S*(f[n]-f[512-n])   (E[0]=S*f[0], O[0]=S*f[256])
//   re[k] = E[0] + (-1)^k O[0] + sum_{n>=1} E[n] cos(2pi n k/512)
//   im[k] =                      sum_{n>=1} O[n] sin(2pi n k/512)
//   k=256: |E[0]+O[0] + sum_{n>=1} (-1)^n E[n]|
// LDS: n-major [256][RSTRIDE]; thread (kg=t&63, fg=t>>6) owns bins k=kg+64u
// (u=0..3) x frames fg*8..fg*8+7. Per n: 4 broadcast b128 serve 80 FMAs
// (64 acc + 16 rotation) -> VALU-bound, LDS @ ~84%.
// ---------------------------------------------------------------------------
__global__ __launch_bounds__(256) void spec_kernel(const float* __restrict__ x,
                                                   const float* __restrict__ w,
                                                   const float* __restrict__ means,
                                                   float* __restrict__ out) {
    __shared__ __align__(16) float lds[256 * RSTRIDE * 2 + 512 + 256];
    float* Es  = lds;                       // [256][RSTRIDE]
    float* Os  = lds + 256 * RSTRIDE;       // [256][RSTRIDE]
    float* wl  = lds + 512 * RSTRIDE;       // [512]
    float* nyq = wl + 512;                  // [8][32]

    const int b  = blockIdx.x;
    const int m0 = blockIdx.y * TM;
    const int t  = threadIdx.x;
    const float mean = means[b];

    wl[t]       = w[t];
    wl[t + 256] = w[t + 256];
    __syncthreads();

    // ---- staging: thread t = n; coalesced fwd + reversed global reads ----
    {
        const int n = t;
        const float* xb = x + (size_t)b * L_LEN + (size_t)m0 * FSTRIDE;
        for (int f = 0; f < TM; ++f) {
            float Ev = 0.f, Ov = 0.f;
            if (m0 + f < M_FRAMES) {
                const float* xf = xb + f * FSTRIDE;
                if (n == 0) {
                    Ev = SQRT_N * ((xf[0]   - mean) * wl[0]);    // E[0]=S*f[0] (w[0]==0)
                    Ov = SQRT_N * ((xf[256] - mean) * wl[256]);  // O[0]=S*f[256]
                } else {
                    float a = (xf[n]       - mean) * wl[n];
                    float c = (xf[512 - n] - mean) * wl[512 - n];
                    Ev = SQRT_N * (a + c);
                    Ov = SQRT_N * (a - c);
                }
            }
            Es[n * RSTRIDE + f] = Ev;   // 8-way bank conflict, ~2% of LDS budget
            Os[n * RSTRIDE + f] = Ov;
        }
    }
    __syncthreads();

    // ---- main: register tile 4 bins x 8 frames ----
    const int kg = t & 63;
    const int fg = t >> 6;
    const float* Er = Es + 8 * fg;
    const float* Or = Os + 8 * fg;

    float re[4][8], im[4][8];

    // init with n=0 terms: re = E0 + (-1)^k O0 (parity of k = parity of kg)
    {
        const float sgn = (kg & 1) ? -1.f : 1.f;
        float4 e0a = *(const float4*)(Er);
        float4 e0b = *(const float4*)(Er + 4);
        float4 o0a = *(const float4*)(Or);
        float4 o0b = *(const float4*)(Or + 4);
        float e0[8] = {e0a.x, e0a.y, e0a.z, e0a.w, e0b.x, e0b.y, e0b.z, e0b.w};
        float o0[8] = {o0a.x, o0a.y, o0a.z, o0a.w, o0b.x, o0b.y, o0b.z, o0b.w};
        #pragma unroll
        for (int u = 0; u < 4; ++u)
            #pragma unroll
            for (int ff = 0; ff < 8; ++ff) {
                re[u][ff] = fmaf(sgn, o0[ff], e0[ff]);
                im[u][ff] = 0.f;
            }
    }

    // per-bin rotation constants: (ck,sk) = e^{2pi i k/512}
    float ck[4], sk[4];
    #pragma unroll
    for (int u = 0; u < 4; ++u) {
        float rev = (float)(kg + 64 * u) * (1.0f / 512.0f);
        ck[u] = hw_cos_rev(rev);
        sk[u] = hw_sin_rev(rev);
    }

    // 4 segments of 64 n-steps; exact trig re-sync at each segment start
    #pragma unroll 1
    for (int seg = 0; seg < 4; ++seg) {
        const int n0   = seg ? seg * 64 : 1;
        const int nend = seg * 64 + 64;
        float c[4], s[4];
        #pragma unroll
        for (int u = 0; u < 4; ++u) {
            int p = (n0 * (kg + 64 * u)) & 511;
            float rev = (float)p * (1.0f / 512.0f);
            c[u] = hw_cos_rev(rev);
            s[u] = hw_sin_rev(rev);
        }
        for (int n = n0; n < nend; ++n) {
            const float* er = Er + n * RSTRIDE;
            const float* orr = Or + n * RSTRIDE;
            float4 ea = *(const float4*)er;
            float4 eb = *(const float4*)(er + 4);
            float4 oa = *(const float4*)orr;
            float4 ob = *(const float4*)(orr + 4);
            #pragma unroll
            for (int u = 0; u < 4; ++u) {
                re[u][0] = fmaf(ea.x, c[u], re[u][0]);  im[u][0] = fmaf(oa.x, s[u], im[u][0]);
                re[u][1] = fmaf(ea.y, c[u], re[u][1]);  im[u][1] = fmaf(oa.y, s[u], im[u][1]);
                re[u][2] = fmaf(ea.z, c[u], re[u][2]);  im[u][2] = fmaf(oa.z, s[u], im[u][2]);
                re[u][3] = fmaf(ea.w, c[u], re[u][3]);  im[u][3] = fmaf(oa.w, s[u], im[u][3]);
                re[u][4] = fmaf(eb.x, c[u], re[u][4]);  im[u][4] = fmaf(ob.x, s[u], im[u][4]);
                re[u][5] = fmaf(eb.y, c[u], re[u][5]);  im[u][5] = fmaf(ob.y, s[u], im[u][5]);
                re[u][6] = fmaf(eb.z, c[u], re[u][6]);  im[u][6] = fmaf(ob.z, s[u], im[u][6]);
                re[u][7] = fmaf(eb.w, c[u], re[u][7]);  im[u][7] = fmaf(ob.w, s[u], im[u][7]);
                // rotate: (c,s) *= (ck,sk)
                float t1 = s[u] * sk[u];
                float t2 = s[u] * ck[u];
                float cn = fmaf(c[u], ck[u], -t1);
                float sn = fmaf(c[u], sk[u],  t2);
                c[u] = cn; s[u] = sn;
            }
        }
    }

    // ---- store bins 0..255 (coalesced: lanes = consecutive k) ----
    #pragma unroll
    for (int u = 0; u < 4; ++u)
        #pragma unroll
        for (int ff = 0; ff < 8; ++ff) {
            const int f = fg * 8 + ff;
            if (m0 + f < M_FRAMES) {
                float r = re[u][ff], i2 = im[u][ff];
                out[((size_t)b * M_FRAMES + (m0 + f)) * KH + kg + 64 * u] =
                    sqrtf(fmaf(r, r, i2 * i2));
            }
        }

    // ---- Nyquist bin k=256: E0 + O0 + sum (-1)^n E[n] ----
    {
        const int g = t >> 5, f = t & 31;
        float acc = 0.f;
        const int nlo = g * 32;
        for (int n2 = nlo; n2 < nlo + 32; n2 += 2) {
            acc += Es[n2 * RSTRIDE + f] - Es[(n2 + 1) * RSTRIDE + f];
        }
        nyq[g * 32 + f] = acc;
    }
    __syncthreads();
    if (t < 32) {
        const int f = t;
        if (m0 + f < M_FRAMES) {
            float acc = Os[f];  // O row 0
            #pragma unroll
            for (int g = 0; g < 8; ++g) acc += nyq[g * 32 + f];
            out[((size_t)b * M_FRAMES + (m0 + f)) * KH + 256] = fabsf(acc);
        }
    }
}

// ---------------------------------------------------------------------------
extern "C" void kernel_launch(void* const* d_in, const int* in_sizes, int n_in,
                              void* d_out, int out_size, void* d_ws, size_t ws_size,
                              hipStream_t stream) {
    const float* x = (const float*)d_in[0];
    const float* w = (const float*)d_in[1];
    float* out   = (float*)d_out;
    float* means = (float*)d_ws;  // 128 floats

    mean_kernel<<<dim3(B_BATCH), dim3(1024), 0, stream>>>(x, means);

    const int mtiles = (M_FRAMES + TM - 1) / TM;  // 16
    spec_kernel<<<dim3(B_BATCH, mtiles), dim3(256), 0, stream>>>(x, w, means, out);
}

// Round 8
// 370.385 us; speedup vs baseline: 1.3988x; 1.0032x over previous
//
#include <hip/hip_runtime.h>
#include <math.h>

// Problem constants (BaseSpectrogram1D)
#define L_LEN    131072
#define M_FRAMES 511
#define N_FFT    512
#define KH       257
#define FSTRIDE  256
#define B_BATCH  128

#define TM       32    // frames per block
#define RSTRIDE  36    // floats per LDS row
#define SQRT_N   22.62741699796952f  // sqrt(512)

typedef float pkf2 __attribute__((ext_vector_type(2)));

// VOP3P packed fp32 (gfx90a+/CDNA): 2 FMAs per instruction
__device__ __forceinline__ pkf2 pk_fma(pkf2 a, pkf2 b, pkf2 c) {
    pkf2 d; asm("v_pk_fma_f32 %0, %1, %2, %3" : "=v"(d) : "v"(a), "v"(b), "v"(c)); return d;
}
__device__ __forceinline__ pkf2 pk_mul(pkf2 a, pkf2 b) {
    pkf2 d; asm("v_pk_mul_f32 %0, %1, %2" : "=v"(d) : "v"(a), "v"(b)); return d;
}
// v_sin/cos_f32 take REVOLUTIONS; p=(n*k)&511 exact -> rev exact fp32
__device__ __forceinline__ float hw_sin_rev(float rev){float r;asm("v_sin_f32 %0, %1":"=v"(r):"v"(rev));return r;}
__device__ __forceinline__ float hw_cos_rev(float rev){float r;asm("v_cos_f32 %0, %1":"=v"(r):"v"(rev));return r;}

// ---------------------------------------------------------------------------
// Kernel 1: partial row sums, 8 chunks per row (1024 blocks -> full GPU).
// Final 8-way reduction is folded into spec_kernel (deterministic).
// ---------------------------------------------------------------------------
__global__ __launch_bounds__(256) void pmean_kernel(const float* __restrict__ x,
                                                    float* __restrict__ partial) {
    const int b = blockIdx.x >> 3, chunk = blockIdx.x & 7;
    const float4* p = (const float4*)(x + (size_t)b * L_LEN + (size_t)chunk * (L_LEN / 8));
    float s = 0.f;
    const int nvec = L_LEN / 8 / 4;  // 4096
    for (int i = threadIdx.x; i < nvec; i += 256) {
        float4 v = p[i];
        s += (v.x + v.y) + (v.z + v.w);
    }
    for (int off = 32; off; off >>= 1) s += __shfl_down(s, off, 64);
    __shared__ float ws[4];
    if ((threadIdx.x & 63) == 0) ws[threadIdx.x >> 6] = s;
    __syncthreads();
    if (threadIdx.x == 0) partial[blockIdx.x] = (ws[0] + ws[1]) + (ws[2] + ws[3]);
}

// ---------------------------------------------------------------------------
// Kernel 2: Hermitian-paired windowed DFT magnitude, packed-fp32 register tile.
//   E[n]=S*(f[n]+f[512-n]), O[n]=S*(f[n]-f[512-n]); E[0]=S*f[0], O[0]=S*f[256]
//   re[k]=E[0]+(-1)^k O[0]+sum E[n]cos(2pi nk/512); im[k]=sum O[n]sin(...)
//   k=256: |E[0]+O[0]+sum (-1)^n E[n]|
// Thread (kg=t&63, fg=t>>6): bins k=kg+64u (u<4) x frames fg*8..fg*8+7 as
// 4x pkf2. Per n-step: 8 broadcast ds_read_b64 + 48 pk-ops (32 acc + 16 rot).
// ---------------------------------------------------------------------------
__global__ __launch_bounds__(256, 2) void spec_kernel(const float* __restrict__ x,
                                                      const float* __restrict__ w,
                                                      const float* __restrict__ partial,
                                                      float* __restrict__ out) {
    __shared__ __align__(16) float lds[256 * RSTRIDE * 2 + 512 + 256];
    float* Es  = lds;                       // [256][RSTRIDE]
    float* Os  = lds + 256 * RSTRIDE;       // [256][RSTRIDE]
    float* wl  = lds + 512 * RSTRIDE;       // [512]
    float* nyq = wl + 512;                  // [8][32]

    const int b  = blockIdx.x;
    const int m0 = blockIdx.y * TM;
    const int t  = threadIdx.x;

    // mean from 8 partials (uniform, deterministic, identical in all blocks)
    float msum = 0.f;
    #pragma unroll
    for (int i = 0; i < 8; ++i) msum += partial[(b << 3) + i];
    const float mean = msum * (1.0f / (float)L_LEN);

    wl[t]       = w[t];
    wl[t + 256] = w[t + 256];
    __syncthreads();

    // ---- staging: thread t = n ----
    {
        const int n = t;
        const float* xb = x + (size_t)b * L_LEN + (size_t)m0 * FSTRIDE;
        for (int f = 0; f < TM; ++f) {
            float Ev = 0.f, Ov = 0.f;
            if (m0 + f < M_FRAMES) {
                const float* xf = xb + f * FSTRIDE;
                if (n == 0) {
                    Ev = SQRT_N * ((xf[0]   - mean) * wl[0]);
                    Ov = SQRT_N * ((xf[256] - mean) * wl[256]);
                } else {
                    float a = (xf[n]       - mean) * wl[n];
                    float c = (xf[512 - n] - mean) * wl[512 - n];
                    Ev = SQRT_N * (a + c);
                    Ov = SQRT_N * (a - c);
                }
            }
            Es[n * RSTRIDE + f] = Ev;
            Os[n * RSTRIDE + f] = Ov;
        }
    }
    __syncthreads();

    // ---- main: packed register tile 4 bins x 8 frames (4x pkf2) ----
    const int kg = t & 63;
    const int fg = t >> 6;
    const float* Er = Es + 8 * fg;
    const float* Or = Os + 8 * fg;

    pkf2 re2[4][4], im2[4][4];

    {   // n=0 init: re = E0 + (-1)^k O0
        const float sg = (kg & 1) ? -1.f : 1.f;
        pkf2 sg2 = {sg, sg};
        #pragma unroll
        for (int j = 0; j < 4; ++j) {
            pkf2 e0 = *(const pkf2*)(Er + 2 * j);
            pkf2 o0 = *(const pkf2*)(Or + 2 * j);
            pkf2 r0 = pk_fma(sg2, o0, e0);
            #pragma unroll
            for (int u = 0; u < 4; ++u) { re2[u][j] = r0; im2[u][j] = (pkf2){0.f, 0.f}; }
        }
    }

    // per-bin rotation constants e^{2pi i k/512}, duplicated-packed
    pkf2 ck2[4], sk2[4], msk2[4];
    #pragma unroll
    for (int u = 0; u < 4; ++u) {
        float rev = (float)(kg + 64 * u) * (1.0f / 512.0f);
        float ck = hw_cos_rev(rev), sk = hw_sin_rev(rev);
        ck2[u]  = (pkf2){ck, ck};
        sk2[u]  = (pkf2){sk, sk};
        msk2[u] = (pkf2){-sk, -sk};
    }

    // 4 segments of <=64 n-steps; exact trig re-sync at segment starts
    #pragma unroll 1
    for (int seg = 0; seg < 4; ++seg) {
        const int n0   = seg ? seg * 64 : 1;
        const int nend = seg * 64 + 64;
        pkf2 c2[4], s2[4];
        #pragma unroll
        for (int u = 0; u < 4; ++u) {
            int p = (n0 * (kg + 64 * u)) & 511;
            float rev = (float)p * (1.0f / 512.0f);
            float c = hw_cos_rev(rev), s = hw_sin_rev(rev);
            c2[u] = (pkf2){c, c};
            s2[u] = (pkf2){s, s};
        }
        #pragma unroll 2
        for (int n = n0; n < nend; ++n) {
            const float* ern = Er + n * RSTRIDE;
            const float* orn = Or + n * RSTRIDE;
            pkf2 e2[4], o2[4];
            #pragma unroll
            for (int j = 0; j < 4; ++j) {
                e2[j] = *(const pkf2*)(ern + 2 * j);  // broadcast ds_read_b64
                o2[j] = *(const pkf2*)(orn + 2 * j);
            }
            #pragma unroll
            for (int u = 0; u < 4; ++u) {
                re2[u][0] = pk_fma(e2[0], c2[u], re2[u][0]);
                im2[u][0] = pk_fma(o2[0], s2[u], im2[u][0]);
                re2[u][1] = pk_fma(e2[1], c2[u], re2[u][1]);
                im2[u][1] = pk_fma(o2[1], s2[u], im2[u][1]);
                re2[u][2] = pk_fma(e2[2], c2[u], re2[u][2]);
                im2[u][2] = pk_fma(o2[2], s2[u], im2[u][2]);
                re2[u][3] = pk_fma(e2[3], c2[u], re2[u][3]);
                im2[u][3] = pk_fma(o2[3], s2[u], im2[u][3]);
                // rotate (c,s) *= (ck,sk), packed on duplicated halves
                pkf2 ta = pk_mul(c2[u], ck2[u]);
                pkf2 tb = pk_mul(c2[u], sk2[u]);
                c2[u] = pk_fma(s2[u], msk2[u], ta);
                s2[u] = pk_fma(s2[u], ck2[u],  tb);
            }
        }
    }

    // ---- store bins 0..255 (lanes = consecutive k -> coalesced) ----
    #pragma unroll
    for (int u = 0; u < 4; ++u) {
        #pragma unroll
        for (int j = 0; j < 4; ++j) {
            const int f0 = fg * 8 + 2 * j;
            if (m0 + f0 < M_FRAMES) {
                float r = re2[u][j].x, ii = im2[u][j].x;
                out[((size_t)b * M_FRAMES + (m0 + f0)) * KH + kg + 64 * u] =
                    sqrtf(fmaf(r, r, ii * ii));
            }
            if (m0 + f0 + 1 < M_FRAMES) {
                float r = re2[u][j].y, ii = im2[u][j].y;
                out[((size_t)b * M_FRAMES + (m0 + f0 + 1)) * KH + kg + 64 * u] =
                    sqrtf(fmaf(r, r, ii * ii));
            }
        }
    }

    // ---- Nyquist bin k=256: E0 + O0 + sum (-1)^n E[n] ----
    {
        const int g = t >> 5, f = t & 31;
        float acc = 0.f;
        const int nlo = g * 32;
        for (int n2 = nlo; n2 < nlo + 32; n2 += 2) {
            acc += Es[n2 * RSTRIDE + f] - Es[(n2 + 1) * RSTRIDE + f];
        }
        nyq[g * 32 + f] = acc;
    }
    __syncthreads();
    if (t < 32) {
        const int f = t;
        if (m0 + f < M_FRAMES) {
            float acc = Os[f];  // O row 0
            #pragma unroll
            for (int g = 0; g < 8; ++g) acc += nyq[g * 32 + f];
            out[((size_t)b * M_FRAMES + (m0 + f)) * KH + 256] = fabsf(acc);
        }
    }
}

// ---------------------------------------------------------------------------
extern "C" void kernel_launch(void* const* d_in, const int* in_sizes, int n_in,
                              void* d_out, int out_size, void* d_ws, size_t ws_size,
                              hipStream_t stream) {
    const float* x = (const float*)d_in[0];
    const float* w = (const float*)d_in[1];
    float* out     = (float*)d_out;
    float* partial = (float*)d_ws;  // 1024 floats

    pmean_kernel<<<dim3(B_BATCH * 8), dim3(256), 0, stream>>>(x, partial);

    const int mtiles = (M_FRAMES + TM - 1) / TM;  // 16
    spec_kernel<<<dim3(B_BATCH, mtiles), dim3(256), 0, stream>>>(x, w, partial, out);
}